// Round 10
// baseline (269.151 us; speedup 1.0000x reference)
//
#include <hip/hip_runtime.h>
#include <math.h>

// Problem constants
#define NB   16
#define CC   256
#define NPTS 16384       // 16*32*32
#define KK   8192
#define Z_OUT 4194304    // NPTS*CC
// d_out: [0,Z_OUT) z_q_out (BCHW), [Z_OUT,Z_OUT+NPTS) idx as float, [Z_OUT+NPTS] loss
// d_out scratch: zb16 = bf16[16384][256] at slot 0, ebf = bf16[8192][256] at slot
// 2,097,152 -- both dead once k_cand completes; k_final overwrites with z_q BCHW.

// ws layout (floats)
#define WS_ENORM 16448
#define WS_CCNT  24640                // int[16384] candidate counts
#define WS_CIDX  41024                // int[16384][64] candidate k lists
#define CAND_CAP 64
#define LCAP     56                   // per-half per-n LDS list capacity
#define MARGIN   4.0e-4f              // > 2*eps_bf16 + d-quantum + enorm spread

typedef short v8s __attribute__((ext_vector_type(8)));
typedef float v4f __attribute__((ext_vector_type(4)));

__device__ __forceinline__ void gl_lds16(const void* g, void* l) {
    __builtin_amdgcn_global_load_lds((const __attribute__((address_space(1))) void*)g,
                                     (__attribute__((address_space(3))) void*)l, 16, 0, 0);
}
__device__ __forceinline__ unsigned short f2bf(float f) {   // RNE, finite inputs
    unsigned int u = __float_as_uint(f);
    return (unsigned short)((u + 0x7FFFu + ((u >> 16) & 1u)) >> 16);
}
// monotone float<->uint encoding for atomicMax on floats of any sign
__device__ __forceinline__ unsigned fenc(float f) {
    unsigned u = __float_as_uint(f);
    return (u & 0x80000000u) ? ~u : (u | 0x80000000u);
}
__device__ __forceinline__ float fdec(unsigned m) {
    unsigned u = (m & 0x80000000u) ? (m & 0x7fffffffu) : ~m;
    return __uint_as_float(u);
}

// ---------------- P0 (fused prep): emb->ebf+enorm, z->zb16, zero accumulators -------
// 3072 blocks x 256 thr. Blocks [0,2048): emb fp32 -> ebf bf16 + enorm (4 rows/blk,
// wave/row); blocks [0,64) additionally zero candCnt; block 0 zeros lossAcc+doneCnt.
// Blocks [2048,3072): z BCHW fp32 -> zb16[n][c] bf16 (round-8 k_prep_z, grid
// dim3(16,4,16) linearized as b2 = bid-2048: x=b2&15, y=(b2>>4)&3, b=b2>>6).
__global__ void k_prep(const float* __restrict__ z, const float* __restrict__ emb,
                       unsigned short* __restrict__ zb16, unsigned short* __restrict__ ebf,
                       float* __restrict__ enorm, float* __restrict__ lossAcc,
                       int* __restrict__ doneCnt, int* __restrict__ candCnt) {
    const int bid = blockIdx.x;
    const int tid = threadIdx.x;
    if (bid < 2048) {
        const int w = tid >> 6, lane = tid & 63;
        const int k = bid * 4 + w;
        const int i = k * CC + lane * 4;
        float4 v = *(const float4*)(emb + i);
        *(ushort4*)(ebf + i) = make_ushort4(f2bf(v.x), f2bf(v.y), f2bf(v.z), f2bf(v.w));
        float s = v.x * v.x + v.y * v.y + v.z * v.z + v.w * v.w;
        for (int off = 32; off > 0; off >>= 1) s += __shfl_down(s, off);
        if (lane == 0) enorm[k] = s;
        if (bid < 64) candCnt[bid * 256 + tid] = 0;
        if (bid == 0 && tid == 0) { lossAcc[0] = 0.0f; doneCnt[0] = 0; }
    } else {
        __shared__ float ts[64][65];
        const int b2 = bid - 2048;
        const int hw0 = (b2 & 15) * 64, c0 = ((b2 >> 4) & 3) * 64, b = b2 >> 6;
#pragma unroll
        for (int p = 0; p < 4; ++p) {
            int u = p * 256 + tid;
            int ci = u >> 4, j4 = (u & 15) << 2;
            float4 v = *(const float4*)(z + (size_t)b * 262144 + (size_t)(c0 + ci) * 1024 + hw0 + j4);
            ts[ci][j4 + 0] = v.x; ts[ci][j4 + 1] = v.y; ts[ci][j4 + 2] = v.z; ts[ci][j4 + 3] = v.w;
        }
        __syncthreads();
#pragma unroll
        for (int p = 0; p < 4; ++p) {
            int u = p * 256 + tid;
            int hj = u >> 4, i4 = (u & 15) << 2;
            ushort4 o = make_ushort4(f2bf(ts[i4 + 0][hj]), f2bf(ts[i4 + 1][hj]),
                                     f2bf(ts[i4 + 2][hj]), f2bf(ts[i4 + 3][hj]));
            *(ushort4*)(zb16 + (size_t)(b * 1024 + hw0 + hj) * 256 + c0 + i4) = o;
        }
    }
}

// ---------------- Phase 1: MFMA candidate generation, 128n x k-half blocks ----------
// A-BW model (fits r4-r8: dur ~ A-traffic/~7TB/s): traffic = #n-tiles x 4MB. This
// round halves it: 128 n-tiles -> 512 MB. 256 blocks = (ntile = bid>>1) x (kh =
// bid&1); block = 128 n x 4096 k. B z-tile (128n x 256c bf16, 64 KB) staged ONCE in
// LDS via gl_lds16; A (e-rows) streamed to regs, depth-1 ping-pong (depth beyond 1
// proven ~nil when BW-bound, r8). Wave w sweeps chunks ci = s*8+w (s=0..7, 64 k),
// strided -> blocks share a sliding L2 window.
// Per cc-step: 8 B ds_read_b128 + 4 A global b128 + 32 MFMA (2x arithmetic
// intensity per A-byte vs r8). Regs: acc 128 + A 32 + B 32 + misc ~25 < 256 at
// (512,2). Spill tripwire: WRITE_SIZE (clean ~0.6 MB).
// Candidates: progressive threshold max(shared half-local runmax, own chunk max) -
// MARGIN -> LDS lists (superset of the half-local margin set). Block-end exact
// filter vs the block's TRUE k-half max; survivors pushed to GLOBAL candI/candCnt
// via device atomics. Correctness of half-local filtering: dot(k*) >= M_global -
// MARGIN >= M_half - MARGIN (M_half <= M_global), so the union over the two
// k-half blocks contains the true argmin. Overflow -> candCnt += KK -> fallback.
// mfma_f32_16x16x32_bf16: A[m=lane&15][c=(lane>>4)*8+j]; B[c][n=lane&15];
// D: col(n)=lane&15, row(k)=(lane>>4)*4+reg.
__global__ __launch_bounds__(512, 2)
void k_cand(const unsigned short* __restrict__ zb16, const unsigned short* __restrict__ ebf,
            int* __restrict__ candCnt, int* __restrict__ candI) {
    __shared__ short    Bs[8][8][512];      // 64 KB  [cchunk][ntile][lane*8]
    __shared__ unsigned runmaxU[128];       // ordered-uint running max per n (half-local)
    __shared__ int      cnt[128];
    __shared__ int      lstK[128][LCAP];    // 28 KB
    __shared__ float    lstD[128][LCAP];    // 28 KB

    const int tid  = threadIdx.x;
    const int lane = tid & 63;
    const int w    = tid >> 6;              // 0..7
    const int nb   = (blockIdx.x >> 1) << 7;   // n-tile base (128 rows)
    const int kh   = blockIdx.x & 1;           // k-half
    const int m16  = lane & 15, q = lane >> 4;

    if (tid < 128) { runmaxU[tid] = 0x007FFFFFu; /* fenc(-inf) */ cnt[tid] = 0; }

    // stage B-tile once: 64 (cc,nt) fragments x 64 lanes x 16B; 8 per wave
#pragma unroll
    for (int p = 0; p < 8; ++p) {
        const int g8 = p * 8 + w;          // 0..63, wave-uniform
        const int cc = g8 >> 3, nt = g8 & 7;
        const unsigned short* g = zb16 + (size_t)(nb + nt * 16 + m16) * 256 + cc * 32 + q * 8;
        gl_lds16(g, &Bs[cc][nt][lane * 8]);
    }

    auto loadA = [&](v8s (&a)[4], int kbr, int cc) {
#pragma unroll
        for (int kt = 0; kt < 4; ++kt)
            a[kt] = *(const v8s*)(ebf + (size_t)(kbr + (kt << 4) + m16) * 256 + (cc << 5) + q * 8);
    };

    v8s aP[4], aN[4];
    const int kb0 = (kh << 12) + (w << 6);   // s=0 chunk
    loadA(aP, kb0, 0);
    __syncthreads();       // Bs staged + runmaxU/cnt init visible (drains vmcnt)

#pragma unroll 1
    for (int s = 0; s < 8; ++s) {
        const int kb  = (kh << 12) + (((s << 3) + w) << 6);   // chunk base (64 k)
        const int kbn = (s < 7) ? kb + 512 : kb;              // next s's chunk
        v4f acc[32];
#pragma unroll
        for (int i = 0; i < 32; ++i) acc[i] = (v4f){0.f, 0.f, 0.f, 0.f};

#pragma unroll
        for (int cc = 0; cc < 8; ++cc) {
            v8s b[8];
#pragma unroll
            for (int nt = 0; nt < 8; ++nt) b[nt] = *(const v8s*)&Bs[cc][nt][lane * 8];
            if ((cc & 1) == 0) {
                loadA(aN, kb, cc + 1);                 // prefetch next cc
#pragma unroll
                for (int kt = 0; kt < 4; ++kt)
#pragma unroll
                    for (int nt = 0; nt < 8; ++nt)
                        acc[kt * 8 + nt] = __builtin_amdgcn_mfma_f32_16x16x32_bf16(
                            aP[kt], b[nt], acc[kt * 8 + nt], 0, 0, 0);
            } else {
                if (cc < 7) loadA(aP, kb, cc + 1);
                else        loadA(aP, kbn, 0);         // prefetch next s across epilogue
#pragma unroll
                for (int kt = 0; kt < 4; ++kt)
#pragma unroll
                    for (int nt = 0; nt < 8; ++nt)
                        acc[kt * 8 + nt] = __builtin_amdgcn_mfma_f32_16x16x32_bf16(
                            aN[kt], b[nt], acc[kt * 8 + nt], 0, 0, 0);
            }
        }

        // chunk epilogue: own-chunk max per n-column, merge into shared runmax, push.
        float mx[8];
#pragma unroll
        for (int nt = 0; nt < 8; ++nt) {
            float m = acc[nt][0];
#pragma unroll
            for (int kt = 0; kt < 4; ++kt)
#pragma unroll
                for (int r = 0; r < 4; ++r) m = fmaxf(m, acc[kt * 8 + nt][r]);
            m = fmaxf(m, __shfl_xor(m, 16));
            m = fmaxf(m, __shfl_xor(m, 32));
            mx[nt] = m;                     // all lanes: chunk max of column nt*16+m16
            if (lane < 16) atomicMax(&runmaxU[nt * 16 + lane], fenc(m));
        }
#pragma unroll
        for (int nt = 0; nt < 8; ++nt) {
            const int nl = nt * 16 + m16;
            const float thr = fmaxf(fdec(runmaxU[nl]), mx[nt]) - MARGIN;
#pragma unroll
            for (int kt = 0; kt < 4; ++kt)
#pragma unroll
                for (int r = 0; r < 4; ++r) {
                    if (acc[kt * 8 + nt][r] >= thr) {
                        int k = kb + (kt << 4) + q * 4 + r;
                        int pos = atomicAdd(&cnt[nl], 1);
                        if (pos < LCAP) { lstK[nl][pos] = k; lstD[nl][pos] = acc[kt * 8 + nt][r]; }
                    }
                }
        }
        if (s == 2 || s == 5) __syncthreads();   // bound cross-wave staleness
    }

    __syncthreads();   // runmaxU now TRUE max of this block's k-half per n
    if (tid < 128) {
        const int n = nb + tid;
        const int c = cnt[tid];
        if (c > LCAP) {
            atomicAdd(&candCnt[n], KK);    // overflow -> force full-scan fallback
        } else {
            const float thr = fdec(runmaxU[tid]) - MARGIN;
            for (int i = 0; i < c; ++i) {
                if (lstD[tid][i] >= thr) {
                    int pos = atomicAdd(&candCnt[n], 1);
                    if (pos < CAND_CAP) candI[(size_t)n * CAND_CAP + pos] = lstK[tid][i];
                }
            }
        }
    }
}

// ---------------- Phase 2 (fused): stage + rescore + gather + loss (+finalize) ------
// 512 blocks x 256 thr (4 waves). Block = 32 consecutive hw (b = bid>>5, hw0 =
// (bid&31)*32); LDS 33.4 KB -> 4 blocks/CU. Rescore: wave per n (8 per wave), lane l
// holds zl[j][4l..4l+3]; zn butterfly shifts all d of an n equally -> argmin/
// tie-break invariant. d = (zn + enorm[k]) - (p+p); ties -> min k (order-invariant,
// robust to the nondeterministic cross-block candidate order). Loss finalized by the
// LAST block via doneCnt (device-scope atomics; __threadfence orders each block's
// lossAcc add before its doneCnt increment; no spin-wait anywhere -> no deadlock).
__global__ __launch_bounds__(256)
void k_final(const float* __restrict__ z, const float* __restrict__ emb,
             const float* __restrict__ enorm, const int* __restrict__ candCnt,
             const int* __restrict__ candI, float* __restrict__ out,
             float* __restrict__ idxf, float* __restrict__ lossAcc,
             int* __restrict__ doneCnt, float* __restrict__ outLoss) {
    __shared__ float zl[32][261];     // [hw][c], 33.4 KB
    __shared__ int   kis[32];
    __shared__ float red[256];
    const int bid = blockIdx.x;
    const int b = bid >> 5, hw0 = (bid & 31) << 5;
    const int tid = threadIdx.x;
    const int lane = tid & 63, w = tid >> 6;

    // stage: read float4 along hw (coalesced), transpose into zl[hw][c]
#pragma unroll
    for (int p = 0; p < 8; ++p) {
        const int u = p * 256 + tid;
        const int c = u >> 3, j4 = (u & 7) << 2;
        float4 v = *(const float4*)(z + (size_t)b * 262144 + (size_t)c * 1024 + hw0 + j4);
        zl[j4 + 0][c] = v.x; zl[j4 + 1][c] = v.y; zl[j4 + 2][c] = v.z; zl[j4 + 3][c] = v.w;
    }
    __syncthreads();

    // rescore: wave per n, 8 n per wave
#pragma unroll 1
    for (int rr = 0; rr < 8; ++rr) {
        const int j = w * 8 + rr;
        const int n = b * 1024 + hw0 + j;
        const float4 zv = *(const float4*)&zl[j][lane * 4];
        float zn = zv.x * zv.x;
        zn = fmaf(zv.y, zv.y, zn); zn = fmaf(zv.z, zv.z, zn); zn = fmaf(zv.w, zv.w, zn);
#pragma unroll
        for (int off = 1; off < 64; off <<= 1) zn += __shfl_xor(zn, off);
        const int cnt = candCnt[n];
        float bd = __builtin_inff();
        int   bk = 0x7fffffff;
        if (cnt <= CAND_CAP) {
#pragma unroll 1
            for (int i = 0; i < cnt; ++i) {
                const int k = candI[(size_t)n * CAND_CAP + i];
                const float4 ev = *(const float4*)(emb + (size_t)k * CC + lane * 4);
                float p = zv.x * ev.x;
                p = fmaf(zv.y, ev.y, p);
                p = fmaf(zv.z, ev.z, p);
                p = fmaf(zv.w, ev.w, p);
#pragma unroll
                for (int off = 1; off < 64; off <<= 1) p += __shfl_xor(p, off);
                const float d = (zn + enorm[k]) - (p + p);
                if (d < bd || (d == bd && k < bk)) { bd = d; bk = k; }
            }
        } else {
            // overflow fallback: exact full scan, ascending k keeps min-k
#pragma unroll 1
            for (int k = 0; k < KK; ++k) {
                const float4 ev = *(const float4*)(emb + (size_t)k * CC + lane * 4);
                float p = zv.x * ev.x;
                p = fmaf(zv.y, ev.y, p);
                p = fmaf(zv.z, ev.z, p);
                p = fmaf(zv.w, ev.w, p);
#pragma unroll
                for (int off = 1; off < 64; off <<= 1) p += __shfl_xor(p, off);
                const float d = (zn + enorm[k]) - (p + p);
                if (d < bd) { bd = d; bk = k; }
            }
        }
        if (lane == 0) { idxf[n] = (float)bk; kis[j] = bk; }
    }
    __syncthreads();

    // gather z_q (BCHW, coalesced along hw) + loss partials from the LDS tile
    const int j  = tid & 31;          // hw within tile
    const int cg = tid >> 5;          // c-group of 32
    const int ki0 = kis[j];
    const float* ep = emb + (size_t)ki0 * CC;
    float ls = 0.0f;
#pragma unroll 4
    for (int c = cg * 32; c < cg * 32 + 32; ++c) {
        float e  = ep[c];
        float zv = zl[j][c];
        out[(size_t)b * 262144 + (size_t)c * 1024 + hw0 + j] = e;
        float df = e - zv;
        ls = fmaf(df, df, ls);
    }
    red[tid] = ls;
    __syncthreads();
    for (int s2 = 128; s2 > 0; s2 >>= 1) {
        if (tid < s2) red[tid] += red[tid + s2];
        __syncthreads();
    }
    if (tid == 0) {
        atomicAdd(lossAcc, red[0]);
        __threadfence();                              // order lossAcc add before counter
        int old = atomicAdd(doneCnt, 1);
        if (old == (int)gridDim.x - 1) {              // last block finalizes loss
            float tot = atomicAdd(lossAcc, 0.0f);     // coherent read after all adds
            float m = tot * (1.0f / 4194304.0f);
            outLoss[0] = m + 0.25f * m;
        }
    }
}

extern "C" void kernel_launch(void* const* d_in, const int* in_sizes, int n_in,
                              void* d_out, int out_size, void* d_ws, size_t ws_size,
                              hipStream_t stream) {
    const float* z   = (const float*)d_in[0];
    const float* emb = (const float*)d_in[1];
    float* outf = (float*)d_out;
    float* wsf  = (float*)d_ws;

    float* lossAcc = wsf;
    int*   doneCnt = (int*)(wsf + 1);
    float* enorm   = wsf + WS_ENORM;
    int*   candCnt = (int*)(wsf + WS_CCNT);
    int*   candI   = (int*)(wsf + WS_CIDX);

    // d_out z_q region doubles as scratch: bf16 zb16/ebf until k_cand completes,
    // then k_final overwrites it with z_q.
    unsigned short* zb16 = (unsigned short*)outf;                  // 8 MB
    unsigned short* ebf  = (unsigned short*)(outf + 2097152);      // 4 MB

    k_prep<<<3072, 256, 0, stream>>>(z, emb, zb16, ebf, enorm, lossAcc, doneCnt, candCnt);
    k_cand<<<256, 512, 0, stream>>>(zb16, ebf, candCnt, candI);
    k_final<<<512, 256, 0, stream>>>(z, emb, enorm, candCnt, candI,
                                     outf, outf + Z_OUT, lossAcc, doneCnt,
                                     outf + Z_OUT + NPTS);
}